// Round 2
// baseline (6018.079 us; speedup 1.0000x reference)
//
#include <hip/hip_runtime.h>
#include <hip/hip_bf16.h>
#include <math.h>

#define TT 64
#define FF 32
#define HH 64
#define G4 256   // 4*H
#define GG1 64
#define GG2 32

__device__ __forceinline__ float sigm(float v){ return 1.0f/(1.0f+expf(-v)); }

// ---------------------------------------------------------------------------
// Fused 2-layer LSTM. Block = 512 threads = 256 gate rows x 2 half-rows,
// processing 2 nodes. thread tid: row j = tid>>1, half s = tid&1.
// Each thread holds HALF of each weight row in registers (112 floats), so no
// spill at <=256 VGPRs. Partial dot products reduced via __shfl_xor(.,1)
// (halves are lane-adjacent). h-state in LDS, c-state in regs of tid<128.
// ---------------------------------------------------------------------------
__global__ __launch_bounds__(512, 2) void lstm_fused(
    const float* __restrict__ x,
    const float* __restrict__ Wih0, const float* __restrict__ Whh0,
    const float* __restrict__ bih0, const float* __restrict__ bhh0,
    const float* __restrict__ Wih1, const float* __restrict__ Whh1,
    const float* __restrict__ bih1, const float* __restrict__ bhh1,
    float* __restrict__ hout, int n)
{
  const int tid = threadIdx.x;
  const int j = tid >> 1;      // gate row 0..255
  const int s = tid & 1;       // half 0/1
  const int nA = blockIdx.x * 2;
  const int nB = nA + 1;
  const bool hasB = (nB < n);

  // half weight rows -> registers (112 floats)
  float wih0[16], whh0[32], wih1[32], whh1[32];
#pragma unroll
  for (int k = 0; k < 16; k += 4) *(float4*)&wih0[k] = *(const float4*)&Wih0[j*FF + s*16 + k];
#pragma unroll
  for (int k = 0; k < 32; k += 4) *(float4*)&whh0[k] = *(const float4*)&Whh0[j*HH + s*32 + k];
#pragma unroll
  for (int k = 0; k < 32; k += 4) *(float4*)&wih1[k] = *(const float4*)&Wih1[j*HH + s*32 + k];
#pragma unroll
  for (int k = 0; k < 32; k += 4) *(float4*)&whh1[k] = *(const float4*)&Whh1[j*HH + s*32 + k];
  const float bias0 = (s == 0) ? (bih0[j] + bhh0[j]) : 0.0f;
  const float bias1 = (s == 0) ? (bih1[j] + bhh1[j]) : 0.0f;

  __shared__ float xs [2][FF];
  __shared__ float h0s[2][HH];
  __shared__ float h1s[2][HH];
  __shared__ float gs [2][G4];

  if (tid < 2*HH) { (&h0s[0][0])[tid] = 0.0f; (&h1s[0][0])[tid] = 0.0f; }
  float c0 = 0.0f, c1 = 0.0f;   // cell state: element (tid&63) of node (tid>>6), tid<128

  const float* xA = x + (size_t)nA * TT * FF;
  const float* xB = hasB ? (x + (size_t)nB * TT * FF) : xA;

  for (int t = 0; t < TT; ++t) {
    if (tid < 64) {
      const int nd = tid >> 5, f = tid & 31;
      xs[nd][f] = (nd ? xB : xA)[t*FF + f];
    }
    __syncthreads();

    // ---- layer 0: a = b0 + x . wih0_half + h0 . whh0_half ----
    float a0 = bias0, a1 = bias0;
    {
      const float4* x0 = (const float4*)&xs [0][s*16];
      const float4* x1 = (const float4*)&xs [1][s*16];
      const float4* h0 = (const float4*)&h0s[0][s*32];
      const float4* h1 = (const float4*)&h0s[1][s*32];
#pragma unroll
      for (int q = 0; q < 4; ++q) {
        float4 v0 = x0[q], v1 = x1[q];
        a0 = fmaf(v0.x, wih0[4*q+0], a0); a1 = fmaf(v1.x, wih0[4*q+0], a1);
        a0 = fmaf(v0.y, wih0[4*q+1], a0); a1 = fmaf(v1.y, wih0[4*q+1], a1);
        a0 = fmaf(v0.z, wih0[4*q+2], a0); a1 = fmaf(v1.z, wih0[4*q+2], a1);
        a0 = fmaf(v0.w, wih0[4*q+3], a0); a1 = fmaf(v1.w, wih0[4*q+3], a1);
      }
#pragma unroll
      for (int q = 0; q < 8; ++q) {
        float4 v0 = h0[q], v1 = h1[q];
        a0 = fmaf(v0.x, whh0[4*q+0], a0); a1 = fmaf(v1.x, whh0[4*q+0], a1);
        a0 = fmaf(v0.y, whh0[4*q+1], a0); a1 = fmaf(v1.y, whh0[4*q+1], a1);
        a0 = fmaf(v0.z, whh0[4*q+2], a0); a1 = fmaf(v1.z, whh0[4*q+2], a1);
        a0 = fmaf(v0.w, whh0[4*q+3], a0); a1 = fmaf(v1.w, whh0[4*q+3], a1);
      }
    }
    a0 += __shfl_xor(a0, 1);
    a1 += __shfl_xor(a1, 1);
    if (s == 0) { gs[0][j] = a0; gs[1][j] = a1; }
    __syncthreads();

    if (tid < 128) {
      const int nd = tid >> 6, m = tid & 63;
      const float gi = gs[nd][m], gf = gs[nd][m+64], gg = gs[nd][m+128], go = gs[nd][m+192];
      c0 = sigm(gf)*c0 + sigm(gi)*tanhf(gg);
      h0s[nd][m] = sigm(go)*tanhf(c0);
    }
    __syncthreads();

    // ---- layer 1: d = b1 + h0_new . wih1_half + h1 . whh1_half ----
    float d0 = bias1, d1 = bias1;
    {
      const float4* p0 = (const float4*)&h0s[0][s*32];
      const float4* p1 = (const float4*)&h0s[1][s*32];
      const float4* q0 = (const float4*)&h1s[0][s*32];
      const float4* q1 = (const float4*)&h1s[1][s*32];
#pragma unroll
      for (int q = 0; q < 8; ++q) {
        float4 v0 = p0[q], v1 = p1[q];
        d0 = fmaf(v0.x, wih1[4*q+0], d0); d1 = fmaf(v1.x, wih1[4*q+0], d1);
        d0 = fmaf(v0.y, wih1[4*q+1], d0); d1 = fmaf(v1.y, wih1[4*q+1], d1);
        d0 = fmaf(v0.z, wih1[4*q+2], d0); d1 = fmaf(v1.z, wih1[4*q+2], d1);
        d0 = fmaf(v0.w, wih1[4*q+3], d0); d1 = fmaf(v1.w, wih1[4*q+3], d1);
      }
#pragma unroll
      for (int q = 0; q < 8; ++q) {
        float4 v0 = q0[q], v1 = q1[q];
        d0 = fmaf(v0.x, whh1[4*q+0], d0); d1 = fmaf(v1.x, whh1[4*q+0], d1);
        d0 = fmaf(v0.y, whh1[4*q+1], d0); d1 = fmaf(v1.y, whh1[4*q+1], d1);
        d0 = fmaf(v0.z, whh1[4*q+2], d0); d1 = fmaf(v1.z, whh1[4*q+2], d1);
        d0 = fmaf(v0.w, whh1[4*q+3], d0); d1 = fmaf(v1.w, whh1[4*q+3], d1);
      }
    }
    d0 += __shfl_xor(d0, 1);
    d1 += __shfl_xor(d1, 1);
    if (s == 0) { gs[0][j] = d0; gs[1][j] = d1; }
    __syncthreads();

    if (tid < 128) {
      const int nd = tid >> 6, m = tid & 63;
      const float gi = gs[nd][m], gf = gs[nd][m+64], gg = gs[nd][m+128], go = gs[nd][m+192];
      c1 = sigm(gf)*c1 + sigm(gi)*tanhf(gg);
      h1s[nd][m] = sigm(go)*tanhf(c1);
    }
    // no barrier here: next-t xs write touches different LDS; the xs barrier
    // orders combine1's gs reads/h1s writes against next-t's gs/h1s uses.
  }
  __syncthreads();
  if (tid < 128) {
    const int nd = tid >> 6, m = tid & 63;
    const int node = nA + nd;
    if (node < n) hout[(size_t)node*HH + m] = h1s[nd][m];
  }
}

// ---------------------------------------------------------------------------
// GCN support kernels (unchanged from round 1 — not the bottleneck)
// ---------------------------------------------------------------------------
__global__ void k_count(const int* __restrict__ dst, int E, int* __restrict__ cnt)
{
  int e = blockIdx.x * blockDim.x + threadIdx.x;
  if (e < E) atomicAdd(&cnt[dst[e]], 1);
}

__global__ void k_scan_build(const int* __restrict__ cnt, int n,
                             int* __restrict__ offs, int* __restrict__ cursor,
                             float* __restrict__ dinv)
{
  __shared__ int part[1024];
  const int tid = threadIdx.x;
  const int per = (n + 1023) >> 10;
  const int base = tid * per;
  int s = 0;
  for (int i = 0; i < per; ++i) { int idx = base + i; if (idx < n) s += cnt[idx]; }
  part[tid] = s;
  __syncthreads();
  for (int off = 1; off < 1024; off <<= 1) {
    int v = 0;
    if (tid >= off) v = part[tid - off];
    __syncthreads();
    part[tid] += v;
    __syncthreads();
  }
  int run = part[tid] - s;
  for (int i = 0; i < per; ++i) {
    int idx = base + i;
    if (idx < n) {
      offs[idx] = run; cursor[idx] = run;
      int c = cnt[idx];
      dinv[idx] = 1.0f / sqrtf((float)(c + 1));
      run += c;
    }
  }
}

__global__ void k_fill(const int* __restrict__ src, const int* __restrict__ dst,
                       int E, int* __restrict__ cursor, int* __restrict__ csr)
{
  int e = blockIdx.x * blockDim.x + threadIdx.x;
  if (e < E) {
    int d = dst[e];
    int pos = atomicAdd(&cursor[d], 1);
    csr[pos] = src[e];
  }
}

template <int K, int M>
__global__ void k_xw(const float* __restrict__ A, const float* __restrict__ W,
                     float* __restrict__ out, int n)
{
  int idx = blockIdx.x * blockDim.x + threadIdx.x;
  int row = idx / M, col = idx % M;
  if (row >= n) return;
  const float* a = A + (size_t)row * K;
  float acc = 0.0f;
#pragma unroll
  for (int k = 0; k < K; ++k) acc = fmaf(a[k], W[k*M + col], acc);
  out[(size_t)row*M + col] = acc;
}

template <int FD>
__global__ void k_agg(const float* __restrict__ xw, const int* __restrict__ offs,
                      const int* __restrict__ cnt, const int* __restrict__ csr,
                      const float* __restrict__ dinv, const float* __restrict__ b,
                      float* __restrict__ out, int n)
{
  int gidx = blockIdx.x * blockDim.x + threadIdx.x;
  int node = gidx / FD, lane = gidx % FD;
  if (node >= n) return;
  const float di = dinv[node];
  float acc = xw[(size_t)node*FD + lane] * di * di;
  const int s0 = offs[node], e0 = s0 + cnt[node];
  for (int p = s0; p < e0; ++p) {
    int s = csr[p];
    acc = fmaf(xw[(size_t)s*FD + lane], dinv[s] * di, acc);
  }
  out[(size_t)node*FD + lane] = fmaxf(acc + b[lane], 0.0f);
}

__global__ void k_fc(const float* __restrict__ g2, const int* __restrict__ sid,
                     const float* __restrict__ fcW, const float* __restrict__ fcb,
                     float* __restrict__ out, int n)
{
  int i = blockIdx.x * blockDim.x + threadIdx.x;
  if (i >= n) return;
  const float* row = g2 + (size_t)sid[i] * GG2;
  float acc = fcb[0];
#pragma unroll
  for (int f = 0; f < GG2; ++f) acc = fmaf(row[f], fcW[f], acc);
  out[i] = acc;
}

// ---------------------------------------------------------------------------
extern "C" void kernel_launch(void* const* d_in, const int* in_sizes, int n_in,
                              void* d_out, int out_size, void* d_ws, size_t ws_size,
                              hipStream_t stream)
{
  const float* x    = (const float*)d_in[0];
  const int*   sid  = (const int*)  d_in[1];
  const int*   eidx = (const int*)  d_in[2];
  const float* Wih0 = (const float*)d_in[3];
  const float* Whh0 = (const float*)d_in[4];
  const float* bih0 = (const float*)d_in[5];
  const float* bhh0 = (const float*)d_in[6];
  const float* Wih1 = (const float*)d_in[7];
  const float* Whh1 = (const float*)d_in[8];
  const float* bih1 = (const float*)d_in[9];
  const float* bhh1 = (const float*)d_in[10];
  const float* g1W  = (const float*)d_in[11];
  const float* g1b  = (const float*)d_in[12];
  const float* g2W  = (const float*)d_in[13];
  const float* g2b  = (const float*)d_in[14];
  const float* fcW  = (const float*)d_in[15];
  const float* fcb  = (const float*)d_in[16];

  const int n = in_sizes[1];
  const int E = in_sizes[2] / 2;
  float* out = (float*)d_out;

  char* w = (char*)d_ws;
  auto carve = [&](size_t bytes) -> void* {
    void* p = (void*)w; w += (bytes + 255) & ~(size_t)255; return p;
  };
  float* hfin   = (float*)carve((size_t)n * HH * 4);
  int*   cnt    = (int*)  carve((size_t)n * 4);
  int*   offs   = (int*)  carve((size_t)n * 4);
  int*   cursor = (int*)  carve((size_t)n * 4);
  float* dinv   = (float*)carve((size_t)n * 4);
  int*   csr    = (int*)  carve((size_t)E * 4);
  float* xw1    = (float*)carve((size_t)n * GG1 * 4);
  float* g1     = (float*)carve((size_t)n * GG1 * 4);
  float* xw2    = (float*)carve((size_t)n * GG2 * 4);
  float* g2     = (float*)carve((size_t)n * GG2 * 4);

  const int* src = eidx;
  const int* dst = eidx + E;

  lstm_fused<<<(n + 1) / 2, 512, 0, stream>>>(x, Wih0, Whh0, bih0, bhh0,
                                              Wih1, Whh1, bih1, bhh1, hfin, n);

  hipMemsetAsync(cnt, 0, (size_t)n * 4, stream);
  k_count<<<(E + 255) / 256, 256, 0, stream>>>(dst, E, cnt);
  k_scan_build<<<1, 1024, 0, stream>>>(cnt, n, offs, cursor, dinv);
  k_fill<<<(E + 255) / 256, 256, 0, stream>>>(src, dst, E, cursor, csr);

  k_xw<HH, GG1><<<((size_t)n * GG1 + 255) / 256, 256, 0, stream>>>(hfin, g1W, xw1, n);
  k_agg<GG1><<<((size_t)n * GG1 + 255) / 256, 256, 0, stream>>>(xw1, offs, cnt, csr, dinv, g1b, g1, n);

  k_xw<GG1, GG2><<<((size_t)n * GG2 + 255) / 256, 256, 0, stream>>>(g1, g2W, xw2, n);
  k_agg<GG2><<<((size_t)n * GG2 + 255) / 256, 256, 0, stream>>>(xw2, offs, cnt, csr, dinv, g2b, g2, n);

  k_fc<<<(n + 255) / 256, 256, 0, stream>>>(g2, sid, fcW, fcb, out, n);
}